// Round 7
// baseline (88.141 us; speedup 1.0000x reference)
//
#include <hip/hip_runtime.h>

// LatencyEncoder R6: persistent grid + pipelined prologue.
// R5 post-mortem: select-stream(85) / nt(85) / LDS-blit(88) all equal ->
// store-stream composition is NOT the limiter. Residual vs the 6.85 TB/s fill
// reference (~62us for our 419MB) modeled as edge exposure: thousands of
// short one-shot blocks each pay input-load latency + f64-exp before their
// first store. Fix: 1024 blocks x 4 chunks, double-buffered lat LDS, next
// chunk's inputs loaded BEFORE the current chunk's 25-float4 store burst.
//
// Numerics unchanged: f64 decision chain matches numpy ref (absmax 0.0 x5).

#define T 100
#define PPC 256   // pairs per chunk (= block width)
#define CPB 4     // chunks per block

typedef float vf4 __attribute__((ext_vector_type(4)));

__device__ __forceinline__ int pair_latency(float xv, float nv) {
  double xn = (double)xv + (double)nv * 0.01;
  double s = 1.0 / (1.0 + exp(-xn));
  int li = (int)rint((1.0 - s) * 99.0);
  li = li < 0 ? 0 : (li > 99 ? 99 : li);
  return (s > 0.5) ? li : -1;  // -1: no spike
}

__global__ __launch_bounds__(256) void latency_encode_kernel(
    const float* __restrict__ x, const float* __restrict__ noise,
    float* __restrict__ out, int npairs) {
  __shared__ int lat_s[2][PPC];

  const int tid = threadIdx.x;
  const long long chunk0 = (long long)blockIdx.x * CPB;
  const long long nchunks = (npairs + PPC - 1) / PPC;

  // ---- prologue: chunk 0 inputs -> latency -> lds buf 0 ----
  {
    const long long p = chunk0 * PPC + tid;
    int lat = -1;
    if (chunk0 < nchunks && p < npairs) lat = pair_latency(x[p], noise[p]);
    lat_s[0][tid] = lat;
  }
  __syncthreads();

  int buf = 0;
#pragma unroll
  for (int k = 0; k < CPB; ++k) {
    const long long c = chunk0 + k;
    if (c >= nchunks) break;

    // issue next chunk's input loads before the store burst (latency hides
    // under the 25-store drain)
    float xv2 = 0.f, nv2 = 0.f;
    bool haveNext = (k + 1 < CPB) && (c + 1 < nchunks);
    if (haveNext) {
      const long long pn = (c + 1) * PPC + tid;
      if (pn < npairs) { xv2 = x[pn]; nv2 = noise[pn]; }
    }

    // ---- store burst: 6400 coalesced float4s for this chunk ----
    vf4* __restrict__ o4 = (vf4*)(out + c * PPC * (long long)T);
    const bool full = (c + 1) * PPC <= npairs;  // always true for 256x4096
    const long long lim4 = full ? 6400 : (npairs - c * PPC) * T / 4;
#pragma unroll
    for (int j = 0; j < 25; ++j) {
      const int fi4 = tid + j * 256;
      const int pl = fi4 / 25;
      const int pos = (fi4 % 25) * 4;
      const int L = lat_s[buf][pl];
      vf4 v;
      v.x = (L == pos + 0) ? 1.0f : 0.0f;
      v.y = (L == pos + 1) ? 1.0f : 0.0f;
      v.z = (L == pos + 2) ? 1.0f : 0.0f;
      v.w = (L == pos + 3) ? 1.0f : 0.0f;
      if (full || fi4 < lim4) o4[fi4] = v;
    }

    // ---- compute next chunk's latencies into the other buffer ----
    if (haveNext) {
      const long long pn = (c + 1) * PPC + tid;
      lat_s[buf ^ 1][tid] = (pn < npairs) ? pair_latency(xv2, nv2) : -1;
      __syncthreads();  // one barrier/chunk: double buffer makes this safe
      buf ^= 1;
    }
  }
}

extern "C" void kernel_launch(void* const* d_in, const int* in_sizes, int n_in,
                              void* d_out, int out_size, void* d_ws, size_t ws_size,
                              hipStream_t stream) {
  const float* x = (const float*)d_in[0];
  const float* noise = (const float*)d_in[1];
  float* out = (float*)d_out;
  const int npairs = in_sizes[0];  // 1,048,576
  const long long nchunks = (npairs + PPC - 1) / PPC;        // 4096
  const int grid = (int)((nchunks + CPB - 1) / CPB);         // 1024
  latency_encode_kernel<<<grid, 256, 0, stream>>>(x, noise, out, npairs);
}

// Round 8
// 79.738 us; speedup vs baseline: 1.1054x; 1.1054x over previous
//
#include <hip/hip_runtime.h>

// LatencyEncoder R7: store-ORDER experiment.
// R0/R4/R5/R6 (select-stream / nt / LDS-blit / pipelined) all 85-88us at
// 5.0 TB/s, while rocclr fill sustains 6.85 TB/s on the same buffer. Last
// untested difference: fill is grid-stride (all waves advance through one
// dense sliding address window -> DRAM row locality); ours was
// block-owns-contiguous-100KB (~1000 disjoint instantaneous streams).
//
// K1: per-pair latency (f64 chain, matches numpy ref bit-exactly, absmax 0.0
//     in all passing rounds) -> u8 table in d_ws (1 MB, L2-resident for K2).
// K2: fill-shaped grid-stride one-hot stream: all-resident 524,288 threads,
//     thread writes float4 i, i += TOT; latency via cached u8 load.
// Fallback: if ws_size < npairs bytes, single-kernel R0 path (correctness).

#define T 100

typedef float vf4 __attribute__((ext_vector_type(4)));

__device__ __forceinline__ int pair_latency_f64(float xv, float nv) {
  double xn = (double)xv + (double)nv * 0.01;
  double s = 1.0 / (1.0 + exp(-xn));
  int li = (int)rint((1.0 - s) * 99.0);
  li = li < 0 ? 0 : (li > 99 ? 99 : li);
  return (s > 0.5) ? li : 255;  // 255: no spike
}

__global__ __launch_bounds__(256) void lat_kernel(
    const float* __restrict__ x, const float* __restrict__ noise,
    unsigned char* __restrict__ lat, int npairs) {
  const int stride = gridDim.x * 256;
  for (int p = blockIdx.x * 256 + threadIdx.x; p < npairs; p += stride)
    lat[p] = (unsigned char)pair_latency_f64(x[p], noise[p]);
}

__global__ __launch_bounds__(256) void onehot_stream_kernel(
    const unsigned char* __restrict__ lat, vf4* __restrict__ o4, int n4) {
  const int stride = gridDim.x * 256;
  for (int i = blockIdx.x * 256 + threadIdx.x; i < n4; i += stride) {
    const int pair = i / 25;              // magic-mul div
    const int pos = (i - pair * 25) * 4;  // element offset within pair
    const int L = lat[pair];              // u8, L1/L2-hit (1 MB table)
    vf4 v;
    v.x = (L == pos + 0) ? 1.0f : 0.0f;
    v.y = (L == pos + 1) ? 1.0f : 0.0f;
    v.z = (L == pos + 2) ? 1.0f : 0.0f;
    v.w = (L == pos + 3) ? 1.0f : 0.0f;
    o4[i] = v;
  }
}

// ---- fallback (R0 structure) if d_ws is too small ----
__global__ __launch_bounds__(256) void latency_encode_fused(
    const float* __restrict__ x, const float* __restrict__ noise,
    float* __restrict__ out, int npairs) {
  __shared__ int lat_s[256];
  const int tid = threadIdx.x;
  const int pairBase = blockIdx.x * 256;
  const int p = pairBase + tid;
  int lat = 255;
  if (p < npairs) lat = pair_latency_f64(x[p], noise[p]);
  lat_s[tid] = lat;
  __syncthreads();
  vf4* o4 = (vf4*)(out + (size_t)pairBase * T);
#pragma unroll
  for (int k = 0; k < 25; ++k) {
    const int fi4 = tid + k * 256;
    const int pl = fi4 / 25;
    const int pos = (fi4 % 25) * 4;
    const int L = lat_s[pl];
    vf4 v;
    v.x = (L == pos + 0) ? 1.0f : 0.0f;
    v.y = (L == pos + 1) ? 1.0f : 0.0f;
    v.z = (L == pos + 2) ? 1.0f : 0.0f;
    v.w = (L == pos + 3) ? 1.0f : 0.0f;
    if (pairBase + pl < npairs) o4[fi4] = v;
  }
}

extern "C" void kernel_launch(void* const* d_in, const int* in_sizes, int n_in,
                              void* d_out, int out_size, void* d_ws, size_t ws_size,
                              hipStream_t stream) {
  const float* x = (const float*)d_in[0];
  const float* noise = (const float*)d_in[1];
  float* out = (float*)d_out;
  const int npairs = in_sizes[0];  // 1,048,576

  if (ws_size >= (size_t)npairs) {
    unsigned char* lat = (unsigned char*)d_ws;
    lat_kernel<<<1024, 256, 0, stream>>>(x, noise, lat, npairs);
    const int n4 = out_size / 4;  // 26,214,400 (out_size % 4 == 0)
    onehot_stream_kernel<<<2048, 256, 0, stream>>>(lat, (vf4*)out, n4);
  } else {
    const int grid = (npairs + 255) / 256;
    latency_encode_fused<<<grid, 256, 0, stream>>>(x, noise, out, npairs);
  }
}